// Round 1
// baseline (1235.393 us; speedup 1.0000x reference)
//
#include <hip/hip_runtime.h>
#include <math.h>

#define NN 50000
#define EE 800000
#define GG 256

__device__ __forceinline__ float gelu_f(float v){
    return 0.5f * v * (1.0f + erff(v * 0.70710678118654752f));
}

// ---------------- degree count over dst ----------------
__global__ __launch_bounds__(256) void k_deg(const int* __restrict__ dst, int* __restrict__ deg, int e){
    int i = blockIdx.x * blockDim.x + threadIdx.x;
    if (i < e) atomicAdd(&deg[dst[i]], 1);
}

// ---------------- single-block exclusive scan + dis ----------------
__global__ __launch_bounds__(1024) void k_scan(const int* __restrict__ deg, int* __restrict__ rp,
                                               int* __restrict__ cursor, float* __restrict__ dis, int n){
    __shared__ int part[1024];
    int t = threadIdx.x;
    int IT = (n + 1023) >> 10;
    int base = t * IT;
    int s = 0;
    for (int i = 0; i < IT; i++){ int idx = base + i; if (idx < n) s += deg[idx]; }
    part[t] = s;
    __syncthreads();
    for (int off = 1; off < 1024; off <<= 1){
        int v = 0;
        if (t >= off) v = part[t - off];
        __syncthreads();
        if (t >= off) part[t] += v;
        __syncthreads();
    }
    int run = part[t] - s;  // exclusive prefix of this thread's chunk
    for (int i = 0; i < IT; i++){
        int idx = base + i;
        if (idx < n){
            int d = deg[idx];
            rp[idx] = run;
            cursor[idx] = run;
            dis[idx] = rsqrtf((float)(d + 1));   // +1 self loop; deg>=1 always
            run += d;
        }
    }
    if (t == 1023) rp[n] = part[1023];
}

// ---------------- CSR fill ----------------
__global__ __launch_bounds__(256) void k_fill(const int* __restrict__ src, const int* __restrict__ dst,
                                              const float* __restrict__ dis, int* __restrict__ cursor,
                                              int* __restrict__ col, float* __restrict__ wn, int e){
    int i = blockIdx.x * blockDim.x + threadIdx.x;
    if (i < e){
        int d = dst[i], s = src[i];
        int p = atomicAdd(&cursor[d], 1);
        col[p] = s;
        wn[p]  = dis[s] * dis[d];
    }
}

// ---------------- dense linear: h = x @ W ----------------
template<int CIN, int COUT>
__global__ __launch_bounds__(256) void k_lin(const float* __restrict__ xin, const float* __restrict__ W,
                                             float* __restrict__ h, int n){
    int i = blockIdx.x * 256 + threadIdx.x;
    int node = i / COUT, c = i % COUT;
    if (node >= n) return;
    float acc = 0.f;
#pragma unroll
    for (int k = 0; k < CIN; k++) acc += xin[node * CIN + k] * W[k * COUT + c];
    h[i] = acc;
}

// ---------------- aggregation + bias + GELU (+ BN stats) ----------------
template<int C, bool STATS>
__global__ __launch_bounds__(256) void k_agg(const float* __restrict__ h, const int* __restrict__ rp,
                                             const int* __restrict__ col, const float* __restrict__ wn,
                                             const float* __restrict__ dis, const float* __restrict__ bias,
                                             float* __restrict__ outp, float* __restrict__ stat, int n){
    int i = blockIdx.x * 256 + threadIdx.x;
    int node = i / C, c = i % C;
    bool valid = node < n;
    float g = 0.f;
    if (valid){
        int beg = rp[node], end = rp[node + 1];
        float acc = 0.f;
        for (int j = beg; j < end; j++) acc += h[col[j] * C + c] * wn[j];
        float dn = dis[node];
        acc += dn * dn * h[node * C + c];   // self loop
        acc += bias[c];
        g = gelu_f(acc);
        outp[i] = g;
    }
    if (STATS){
        __shared__ float ss[256], sq[256];
        int t = threadIdx.x;
        ss[t] = g; sq[t] = g * g;
        __syncthreads();
        for (int off = 128; off >= C; off >>= 1){
            if (t < off){ ss[t] += ss[t + off]; sq[t] += sq[t + off]; }
            __syncthreads();
        }
        if (t < C){
            atomicAdd(&stat[t], ss[t]);
            atomicAdd(&stat[128 + t], sq[t]);
        }
    }
}

// ---------------- aggregation + bias + GELU + mean-pool atomics (layer 4) ----------------
__global__ __launch_bounds__(256) void k_agg_pool(const float* __restrict__ h, const int* __restrict__ rp,
                                                  const int* __restrict__ col, const float* __restrict__ wn,
                                                  const float* __restrict__ dis, const float* __restrict__ bias,
                                                  const int* __restrict__ batch, float* __restrict__ pool,
                                                  float* __restrict__ cnt, int n){
    const int C = 128;
    int i = blockIdx.x * 256 + threadIdx.x;
    int node = i / C, c = i % C;
    if (node >= n) return;
    int beg = rp[node], end = rp[node + 1];
    float acc = 0.f;
    for (int j = beg; j < end; j++) acc += h[col[j] * C + c] * wn[j];
    float dn = dis[node];
    acc += dn * dn * h[node * C + c];
    acc += bias[c];
    float g = gelu_f(acc);
    int gr = batch[node];
    atomicAdd(&pool[gr * C + c], g);
    if (c == 0) atomicAdd(&cnt[gr], 1.0f);
}

// ---------------- BatchNorm apply (in place) ----------------
template<int C>
__global__ __launch_bounds__(256) void k_bn(float* __restrict__ buf, const float* __restrict__ stat,
                                            const float* __restrict__ gamma, const float* __restrict__ beta,
                                            int n){
    int i = blockIdx.x * 256 + threadIdx.x;
    if (i >= n * C) return;
    int c = i % C;
    const float invn = 1.0f / (float)NN;
    float mean = stat[c] * invn;
    float var  = stat[128 + c] * invn - mean * mean;
    buf[i] = gamma[c] * (buf[i] - mean) * rsqrtf(var + 1e-5f) + beta[c];
}

// ---------------- MLP head: 256 graphs, one block each ----------------
__global__ __launch_bounds__(128) void k_mlp(const float* __restrict__ pool, const float* __restrict__ cnt,
                                             const float* __restrict__ yex,
                                             const float* __restrict__ lw1, const float* __restrict__ lb1,
                                             const float* __restrict__ lw2, const float* __restrict__ lb2,
                                             const float* __restrict__ lw3, const float* __restrict__ lb3,
                                             const float* __restrict__ lw4, const float* __restrict__ lb4,
                                             float* __restrict__ outp){
    int g = blockIdx.x;
    int t = threadIdx.x;
    __shared__ float z[136];
    __shared__ float z2[128];
    __shared__ float z3[64];
    __shared__ float z4[32];
    float cdiv = fmaxf(cnt[g], 1.0f);
    z[t] = pool[g * 128 + t] / cdiv;
    if (t < 7) z[128 + t] = yex[g * 7 + t];
    __syncthreads();
    {   // 135 -> 128
        float acc = lb1[t];
        for (int k = 0; k < 135; k++) acc += z[k] * lw1[k * 128 + t];
        z2[t] = gelu_f(acc);
    }
    __syncthreads();
    if (t < 64){   // 128 -> 64
        float acc = lb2[t];
        for (int k = 0; k < 128; k++) acc += z2[k] * lw2[k * 64 + t];
        z3[t] = gelu_f(acc);
    }
    __syncthreads();
    if (t < 32){   // 64 -> 32
        float acc = lb3[t];
        for (int k = 0; k < 64; k++) acc += z3[k] * lw3[k * 32 + t];
        z4[t] = gelu_f(acc);
    }
    __syncthreads();
    if (t < 2){    // 32 -> 2, sigmoid
        float acc = lb4[t];
        for (int k = 0; k < 32; k++) acc += z4[k] * lw4[k * 2 + t];
        outp[g * 2 + t] = 1.0f / (1.0f + expf(-acc));
    }
}

extern "C" void kernel_launch(void* const* d_in, const int* in_sizes, int n_in,
                              void* d_out, int out_size, void* d_ws, size_t ws_size,
                              hipStream_t stream) {
    const float* x     = (const float*)d_in[0];
    const int*   ei    = (const int*)  d_in[1];   // [2, E]: src = ei, dst = ei+E
    const int*   batch = (const int*)  d_in[2];
    const float* yex   = (const float*)d_in[3];
    const float* W1 = (const float*)d_in[4];  const float* b1 = (const float*)d_in[5];
    const float* W2 = (const float*)d_in[6];  const float* b2 = (const float*)d_in[7];
    const float* W3 = (const float*)d_in[8];  const float* b3 = (const float*)d_in[9];
    const float* W4 = (const float*)d_in[10]; const float* b4 = (const float*)d_in[11];
    const float* g1 = (const float*)d_in[12]; const float* be1 = (const float*)d_in[13];
    const float* g2 = (const float*)d_in[14]; const float* be2 = (const float*)d_in[15];
    const float* g3 = (const float*)d_in[16]; const float* be3 = (const float*)d_in[17];
    const float* lw1 = (const float*)d_in[18]; const float* lb1 = (const float*)d_in[19];
    const float* lw2 = (const float*)d_in[20]; const float* lb2 = (const float*)d_in[21];
    const float* lw3 = (const float*)d_in[22]; const float* lb3 = (const float*)d_in[23];
    const float* lw4 = (const float*)d_in[24]; const float* lb4 = (const float*)d_in[25];
    float* out = (float*)d_out;

    // ---- workspace carve (256B-aligned) ----
    char* wsb = (char*)d_ws;
    size_t off = 0;
    auto alloc = [&](size_t elems) -> void* {
        void* p = wsb + off;
        off += ((elems * 4 + 255) / 256) * 256;
        return p;
    };
    int*   deg    = (int*)  alloc(NN);
    float* stats  = (float*)alloc(3 * 256);      // per layer l: [l*256 .. l*256+C)=sum, [l*256+128 ..)=sumsq
    float* pool   = (float*)alloc(GG * 128);
    float* cntv   = (float*)alloc(GG);
    size_t zero_bytes = off;                     // everything above must start at 0
    int*   rp     = (int*)  alloc(NN + 1);
    int*   cursor = (int*)  alloc(NN);
    float* dis    = (float*)alloc(NN);
    int*   col    = (int*)  alloc(EE);
    float* wn     = (float*)alloc(EE);
    float* hbuf   = (float*)alloc((size_t)NN * 128);
    float* abuf   = (float*)alloc((size_t)NN * 128);

    hipMemsetAsync(d_ws, 0, zero_bytes, stream);

    auto nb = [](long long total){ return (int)((total + 255) / 256); };

    // ---- graph norm precompute ----
    k_deg <<<nb(EE), 256, 0, stream>>>(ei + EE, deg, EE);
    k_scan<<<1, 1024, 0, stream>>>(deg, rp, cursor, dis, NN);
    k_fill<<<nb(EE), 256, 0, stream>>>(ei, ei + EE, dis, cursor, col, wn, EE);

    // ---- layer 1: 1 -> 16 ----
    k_lin<1, 16>  <<<nb((long long)NN * 16), 256, 0, stream>>>(x, W1, hbuf, NN);
    k_agg<16, true><<<nb((long long)NN * 16), 256, 0, stream>>>(hbuf, rp, col, wn, dis, b1, abuf, stats + 0, NN);
    k_bn<16>      <<<nb((long long)NN * 16), 256, 0, stream>>>(abuf, stats + 0, g1, be1, NN);

    // ---- layer 2: 16 -> 32 ----
    k_lin<16, 32> <<<nb((long long)NN * 32), 256, 0, stream>>>(abuf, W2, hbuf, NN);
    k_agg<32, true><<<nb((long long)NN * 32), 256, 0, stream>>>(hbuf, rp, col, wn, dis, b2, abuf, stats + 256, NN);
    k_bn<32>      <<<nb((long long)NN * 32), 256, 0, stream>>>(abuf, stats + 256, g2, be2, NN);

    // ---- layer 3: 32 -> 64 ----
    k_lin<32, 64> <<<nb((long long)NN * 64), 256, 0, stream>>>(abuf, W3, hbuf, NN);
    k_agg<64, true><<<nb((long long)NN * 64), 256, 0, stream>>>(hbuf, rp, col, wn, dis, b3, abuf, stats + 512, NN);
    k_bn<64>      <<<nb((long long)NN * 64), 256, 0, stream>>>(abuf, stats + 512, g3, be3, NN);

    // ---- layer 4: 64 -> 128, fused pool ----
    k_lin<64, 128><<<nb((long long)NN * 128), 256, 0, stream>>>(abuf, W4, hbuf, NN);
    k_agg_pool    <<<nb((long long)NN * 128), 256, 0, stream>>>(hbuf, rp, col, wn, dis, b4, batch, pool, cntv, NN);

    // ---- MLP head ----
    k_mlp<<<GG, 128, 0, stream>>>(pool, cntv, yex,
                                  lw1, lb1, lw2, lb2, lw3, lb3, lw4, lb4, out);
}

// Round 2
// 1154.167 us; speedup vs baseline: 1.0704x; 1.0704x over previous
//
#include <hip/hip_runtime.h>
#include <math.h>

#define NN 50000
#define EE 800000
#define GG 256

__device__ __forceinline__ float gelu_f(float v){
    return 0.5f * v * (1.0f + erff(v * 0.70710678118654752f));
}

// ---------------- degree count over dst ----------------
__global__ __launch_bounds__(256) void k_deg(const int* __restrict__ dst, int* __restrict__ deg, int e){
    int i = blockIdx.x * blockDim.x + threadIdx.x;
    if (i < e) atomicAdd(&deg[dst[i]], 1);
}

// ---------------- single-block exclusive scan + dis ----------------
__global__ __launch_bounds__(1024) void k_scan(const int* __restrict__ deg, int* __restrict__ rp,
                                               int* __restrict__ cursor, float* __restrict__ dis, int n){
    __shared__ int part[1024];
    int t = threadIdx.x;
    int IT = (n + 1023) >> 10;
    int base = t * IT;
    int s = 0;
    for (int i = 0; i < IT; i++){ int idx = base + i; if (idx < n) s += deg[idx]; }
    part[t] = s;
    __syncthreads();
    for (int off = 1; off < 1024; off <<= 1){
        int v = 0;
        if (t >= off) v = part[t - off];
        __syncthreads();
        if (t >= off) part[t] += v;
        __syncthreads();
    }
    int run = part[t] - s;  // exclusive prefix of this thread's chunk
    for (int i = 0; i < IT; i++){
        int idx = base + i;
        if (idx < n){
            int d = deg[idx];
            rp[idx] = run;
            cursor[idx] = run;
            dis[idx] = rsqrtf((float)(d + 1));   // +1 self loop
            run += d;
        }
    }
    if (t == 1023) rp[n] = part[1023];
}

// ---------------- CSR fill ----------------
__global__ __launch_bounds__(256) void k_fill(const int* __restrict__ src, const int* __restrict__ dst,
                                              const float* __restrict__ dis, int* __restrict__ cursor,
                                              int* __restrict__ col, float* __restrict__ wn, int e){
    int i = blockIdx.x * blockDim.x + threadIdx.x;
    if (i < e){
        int d = dst[i], s = src[i];
        int p = atomicAdd(&cursor[d], 1);
        col[p] = s;
        wn[p]  = dis[s] * dis[d];
    }
}

// ---------------- layer-1 aggregation of x (C=1): edge-parallel atomics + self loop ----------------
__global__ __launch_bounds__(256) void k_agg1(const float* __restrict__ x, const int* __restrict__ src,
                                              const int* __restrict__ dst, const float* __restrict__ dis,
                                              float* __restrict__ agg, int e, int n){
    int i = blockIdx.x * blockDim.x + threadIdx.x;
    if (i < e){
        int s = src[i], d = dst[i];
        atomicAdd(&agg[d], x[s] * dis[s] * dis[d]);
    } else if (i < e + n){
        int node = i - e;
        float dn = dis[node];
        atomicAdd(&agg[node], dn * dn * x[node]);
    }
}

// ---------------- gather with inline BN of previous layer (float4, 4 ch/thread) ----------------
template<int C>
__global__ __launch_bounds__(256) void k_gather(const float* __restrict__ h, const int* __restrict__ rp,
                                                const int* __restrict__ col, const float* __restrict__ wn,
                                                const float* __restrict__ dis, const float* __restrict__ stat,
                                                const float* __restrict__ gamma, const float* __restrict__ beta,
                                                float* __restrict__ outp, int n){
    constexpr int TPN = C / 4;
    int i = blockIdx.x * 256 + threadIdx.x;
    int node = i / TPN, q = i % TPN;
    if (node >= n) return;
    int c0 = q * 4;
    const float invn = 1.0f / (float)NN;
    float scv[4], shv[4];
#pragma unroll
    for (int u = 0; u < 4; u++){
        float mean = stat[c0 + u] * invn;
        float var  = stat[128 + c0 + u] * invn - mean * mean;
        float sc   = gamma[c0 + u] * rsqrtf(var + 1e-5f);
        scv[u] = sc;
        shv[u] = beta[c0 + u] - mean * sc;
    }
    const float4* h4 = (const float4*)h;
    int beg = rp[node], end = rp[node + 1];
    float a0 = 0.f, a1 = 0.f, a2 = 0.f, a3 = 0.f;
    for (int j = beg; j < end; j++){
        float w = wn[j];
        float4 v = h4[col[j] * TPN + q];
        a0 += (v.x * scv[0] + shv[0]) * w;
        a1 += (v.y * scv[1] + shv[1]) * w;
        a2 += (v.z * scv[2] + shv[2]) * w;
        a3 += (v.w * scv[3] + shv[3]) * w;
    }
    float dn = dis[node];
    float ws = dn * dn;
    float4 vs = h4[node * TPN + q];
    a0 += (vs.x * scv[0] + shv[0]) * ws;
    a1 += (vs.y * scv[1] + shv[1]) * ws;
    a2 += (vs.z * scv[2] + shv[2]) * ws;
    a3 += (vs.w * scv[3] + shv[3]) * ws;
    ((float4*)outp)[node * TPN + q] = make_float4(a0, a1, a2, a3);
}

// ---------------- dense linear + bias + GELU (+BN stats): h = gelu(a@W + b) ----------------
template<int CIN, int COUT, bool STATS>
__global__ __launch_bounds__(256) void k_lin(const float* __restrict__ xin, const float* __restrict__ W,
                                             const float* __restrict__ bias, float* __restrict__ outp,
                                             float* __restrict__ stat, int n){
    int i = blockIdx.x * 256 + threadIdx.x;
    int node = i / COUT, c = i % COUT;
    bool valid = node < n;
    float g = 0.f;
    if (valid){
        float acc = bias[c];
#pragma unroll
        for (int k = 0; k < CIN; k++) acc += xin[node * CIN + k] * W[k * COUT + c];
        g = gelu_f(acc);
        outp[i] = g;
    }
    if (STATS){
        __shared__ float ss[256], sq[256];
        int t = threadIdx.x;
        ss[t] = g; sq[t] = g * g;
        __syncthreads();
        for (int off = 128; off >= COUT; off >>= 1){
            if (t < off){ ss[t] += ss[t + off]; sq[t] += sq[t + off]; }
            __syncthreads();
        }
        if (t < COUT){
            atomicAdd(&stat[t], ss[t]);
            atomicAdd(&stat[128 + t], sq[t]);
        }
    }
}

// ---------------- layer-4 linear + bias + GELU + mean-pool atomics (no h4 materialization) ----------------
__global__ __launch_bounds__(256) void k_l4pool(const float* __restrict__ xin, const float* __restrict__ W,
                                                const float* __restrict__ bias, const int* __restrict__ batch,
                                                float* __restrict__ pool, float* __restrict__ cnt, int n){
    const int CIN = 64, COUT = 128;
    int i = blockIdx.x * 256 + threadIdx.x;
    int node = i / COUT, c = i % COUT;
    if (node >= n) return;
    float acc = bias[c];
#pragma unroll
    for (int k = 0; k < CIN; k++) acc += xin[node * CIN + k] * W[k * COUT + c];
    float g = gelu_f(acc);
    int gr = batch[node];
    atomicAdd(&pool[gr * COUT + c], g);
    if (c == 0) atomicAdd(&cnt[gr], 1.0f);
}

// ---------------- MLP head: 256 graphs, one block each ----------------
__global__ __launch_bounds__(128) void k_mlp(const float* __restrict__ pool, const float* __restrict__ cnt,
                                             const float* __restrict__ yex,
                                             const float* __restrict__ lw1, const float* __restrict__ lb1,
                                             const float* __restrict__ lw2, const float* __restrict__ lb2,
                                             const float* __restrict__ lw3, const float* __restrict__ lb3,
                                             const float* __restrict__ lw4, const float* __restrict__ lb4,
                                             float* __restrict__ outp){
    int g = blockIdx.x;
    int t = threadIdx.x;
    __shared__ float z[136];
    __shared__ float z2[128];
    __shared__ float z3[64];
    __shared__ float z4[32];
    float cdiv = fmaxf(cnt[g], 1.0f);
    z[t] = pool[g * 128 + t] / cdiv;
    if (t < 7) z[128 + t] = yex[g * 7 + t];
    __syncthreads();
    {   // 135 -> 128
        float acc = lb1[t];
        for (int k = 0; k < 135; k++) acc += z[k] * lw1[k * 128 + t];
        z2[t] = gelu_f(acc);
    }
    __syncthreads();
    if (t < 64){   // 128 -> 64
        float acc = lb2[t];
        for (int k = 0; k < 128; k++) acc += z2[k] * lw2[k * 64 + t];
        z3[t] = gelu_f(acc);
    }
    __syncthreads();
    if (t < 32){   // 64 -> 32
        float acc = lb3[t];
        for (int k = 0; k < 64; k++) acc += z3[k] * lw3[k * 32 + t];
        z4[t] = gelu_f(acc);
    }
    __syncthreads();
    if (t < 2){    // 32 -> 2, sigmoid
        float acc = lb4[t];
        for (int k = 0; k < 32; k++) acc += z4[k] * lw4[k * 2 + t];
        outp[g * 2 + t] = 1.0f / (1.0f + expf(-acc));
    }
}

extern "C" void kernel_launch(void* const* d_in, const int* in_sizes, int n_in,
                              void* d_out, int out_size, void* d_ws, size_t ws_size,
                              hipStream_t stream) {
    const float* x     = (const float*)d_in[0];
    const int*   ei    = (const int*)  d_in[1];   // [2, E]: src = ei, dst = ei+E
    const int*   batch = (const int*)  d_in[2];
    const float* yex   = (const float*)d_in[3];
    const float* W1 = (const float*)d_in[4];  const float* b1 = (const float*)d_in[5];
    const float* W2 = (const float*)d_in[6];  const float* b2 = (const float*)d_in[7];
    const float* W3 = (const float*)d_in[8];  const float* b3 = (const float*)d_in[9];
    const float* W4 = (const float*)d_in[10]; const float* b4 = (const float*)d_in[11];
    const float* g1 = (const float*)d_in[12]; const float* be1 = (const float*)d_in[13];
    const float* g2 = (const float*)d_in[14]; const float* be2 = (const float*)d_in[15];
    const float* g3 = (const float*)d_in[16]; const float* be3 = (const float*)d_in[17];
    const float* lw1 = (const float*)d_in[18]; const float* lb1 = (const float*)d_in[19];
    const float* lw2 = (const float*)d_in[20]; const float* lb2 = (const float*)d_in[21];
    const float* lw3 = (const float*)d_in[22]; const float* lb3 = (const float*)d_in[23];
    const float* lw4 = (const float*)d_in[24]; const float* lb4 = (const float*)d_in[25];
    float* out = (float*)d_out;

    // ---- workspace carve (256B-aligned); zero-region first ----
    char* wsb = (char*)d_ws;
    size_t off = 0;
    auto alloc = [&](size_t elems) -> void* {
        void* p = wsb + off;
        off += ((elems * 4 + 255) / 256) * 256;
        return p;
    };
    int*   deg    = (int*)  alloc(NN);
    float* stats  = (float*)alloc(3 * 256);      // layer l: [l*256+c]=sum, [l*256+128+c]=sumsq
    float* pool   = (float*)alloc(GG * 128);
    float* cntv   = (float*)alloc(GG);
    float* agg1   = (float*)alloc(NN);
    size_t zero_bytes = off;
    int*   rp     = (int*)  alloc(NN + 1);
    int*   cursor = (int*)  alloc(NN);
    float* dis    = (float*)alloc(NN);
    int*   col    = (int*)  alloc(EE);
    float* wn     = (float*)alloc(EE);
    float* hbuf   = (float*)alloc((size_t)NN * 64);   // raw gelu outputs (<=64 ch)
    float* abuf   = (float*)alloc((size_t)NN * 64);   // aggregated inputs (<=64 ch)

    hipMemsetAsync(d_ws, 0, zero_bytes, stream);

    auto nb = [](long long total){ return (int)((total + 255) / 256); };

    // ---- graph norm precompute ----
    k_deg <<<nb(EE), 256, 0, stream>>>(ei + EE, deg, EE);
    k_scan<<<1, 1024, 0, stream>>>(deg, rp, cursor, dis, NN);
    k_fill<<<nb(EE), 256, 0, stream>>>(ei, ei + EE, dis, cursor, col, wn, EE);

    // ---- layer 1: aggregate x (C=1), then 1->16 linear+gelu+stats ----
    k_agg1<<<nb(EE + NN), 256, 0, stream>>>(x, ei, ei + EE, dis, agg1, EE, NN);
    k_lin<1, 16, true><<<nb((long long)NN * 16), 256, 0, stream>>>(agg1, W1, b1, hbuf, stats + 0, NN);

    // ---- layer 2: gather h1 (BN1 inline, C=16), 16->32 linear+gelu+stats ----
    k_gather<16><<<nb((long long)NN * 4), 256, 0, stream>>>(hbuf, rp, col, wn, dis, stats + 0, g1, be1, abuf, NN);
    k_lin<16, 32, true><<<nb((long long)NN * 32), 256, 0, stream>>>(abuf, W2, b2, hbuf, stats + 256, NN);

    // ---- layer 3: gather h2 (BN2 inline, C=32), 32->64 linear+gelu+stats ----
    k_gather<32><<<nb((long long)NN * 8), 256, 0, stream>>>(hbuf, rp, col, wn, dis, stats + 256, g2, be2, abuf, NN);
    k_lin<32, 64, true><<<nb((long long)NN * 64), 256, 0, stream>>>(abuf, W3, b3, hbuf, stats + 512, NN);

    // ---- layer 4: gather h3 (BN3 inline, C=64), 64->128 linear+gelu+pool (fused) ----
    k_gather<64><<<nb((long long)NN * 16), 256, 0, stream>>>(hbuf, rp, col, wn, dis, stats + 512, g3, be3, abuf, NN);
    k_l4pool<<<nb((long long)NN * 128), 256, 0, stream>>>(abuf, W4, b4, batch, pool, cntv, NN);

    // ---- MLP head ----
    k_mlp<<<GG, 128, 0, stream>>>(pool, cntv, yex,
                                  lw1, lb1, lw2, lb2, lw3, lb3, lw4, lb4, out);
}

// Round 3
// 640.999 us; speedup vs baseline: 1.9273x; 1.8006x over previous
//
#include <hip/hip_runtime.h>
#include <math.h>

#define NN 50000
#define EE 800000
#define GG 256

__device__ __forceinline__ float gelu_f(float v){
    return 0.5f * v * (1.0f + erff(v * 0.70710678118654752f));
}

// ---------------- degree count over dst ----------------
__global__ __launch_bounds__(256) void k_deg(const int* __restrict__ dst, int* __restrict__ deg, int e){
    int i = blockIdx.x * blockDim.x + threadIdx.x;
    if (i < e) atomicAdd(&deg[dst[i]], 1);
}

// ---------------- single-block exclusive scan + dis ----------------
__global__ __launch_bounds__(1024) void k_scan(const int* __restrict__ deg, int* __restrict__ rp,
                                               int* __restrict__ cursor, float* __restrict__ dis, int n){
    __shared__ int part[1024];
    int t = threadIdx.x;
    int IT = (n + 1023) >> 10;
    int base = t * IT;
    int s = 0;
    for (int i = 0; i < IT; i++){ int idx = base + i; if (idx < n) s += deg[idx]; }
    part[t] = s;
    __syncthreads();
    for (int off = 1; off < 1024; off <<= 1){
        int v = 0;
        if (t >= off) v = part[t - off];
        __syncthreads();
        if (t >= off) part[t] += v;
        __syncthreads();
    }
    int run = part[t] - s;  // exclusive prefix of this thread's chunk
    for (int i = 0; i < IT; i++){
        int idx = base + i;
        if (idx < n){
            int d = deg[idx];
            rp[idx] = run;
            cursor[idx] = run;
            dis[idx] = rsqrtf((float)(d + 1));   // +1 self loop
            run += d;
        }
    }
    if (t == 1023) rp[n] = part[1023];
}

// ---------------- CSR fill ----------------
__global__ __launch_bounds__(256) void k_fill(const int* __restrict__ src, const int* __restrict__ dst,
                                              const float* __restrict__ dis, int* __restrict__ cursor,
                                              int* __restrict__ col, float* __restrict__ wn, int e){
    int i = blockIdx.x * blockDim.x + threadIdx.x;
    if (i < e){
        int d = dst[i], s = src[i];
        int p = atomicAdd(&cursor[d], 1);
        col[p] = s;
        wn[p]  = dis[s] * dis[d];
    }
}

// ---------------- layer-1 aggregation of x (C=1): edge-parallel atomics + self loop ----------------
__global__ __launch_bounds__(256) void k_agg1(const float* __restrict__ x, const int* __restrict__ src,
                                              const int* __restrict__ dst, const float* __restrict__ dis,
                                              float* __restrict__ agg, int e, int n){
    int i = blockIdx.x * blockDim.x + threadIdx.x;
    if (i < e){
        int s = src[i], d = dst[i];
        atomicAdd(&agg[d], x[s] * dis[s] * dis[d]);
    } else if (i < e + n){
        int node = i - e;
        float dn = dis[node];
        atomicAdd(&agg[node], dn * dn * x[node]);
    }
}

// ---------------- gather with inline BN of previous layer (float4, 4 ch/thread) ----------------
template<int C>
__global__ __launch_bounds__(256) void k_gather(const float* __restrict__ h, const int* __restrict__ rp,
                                                const int* __restrict__ col, const float* __restrict__ wn,
                                                const float* __restrict__ dis, const float* __restrict__ stat,
                                                const float* __restrict__ gamma, const float* __restrict__ beta,
                                                float* __restrict__ outp, int n){
    constexpr int TPN = C / 4;
    int i = blockIdx.x * 256 + threadIdx.x;
    int node = i / TPN, q = i % TPN;
    if (node >= n) return;
    int c0 = q * 4;
    const float invn = 1.0f / (float)NN;
    float scv[4], shv[4];
#pragma unroll
    for (int u = 0; u < 4; u++){
        float mean = stat[c0 + u] * invn;
        float var  = stat[128 + c0 + u] * invn - mean * mean;
        float sc   = gamma[c0 + u] * rsqrtf(var + 1e-5f);
        scv[u] = sc;
        shv[u] = beta[c0 + u] - mean * sc;
    }
    const float4* h4 = (const float4*)h;
    int beg = rp[node], end = rp[node + 1];
    float a0 = 0.f, a1 = 0.f, a2 = 0.f, a3 = 0.f;
    for (int j = beg; j < end; j++){
        float w = wn[j];
        float4 v = h4[col[j] * TPN + q];
        a0 += (v.x * scv[0] + shv[0]) * w;
        a1 += (v.y * scv[1] + shv[1]) * w;
        a2 += (v.z * scv[2] + shv[2]) * w;
        a3 += (v.w * scv[3] + shv[3]) * w;
    }
    float dn = dis[node];
    float ws = dn * dn;
    float4 vs = h4[node * TPN + q];
    a0 += (vs.x * scv[0] + shv[0]) * ws;
    a1 += (vs.y * scv[1] + shv[1]) * ws;
    a2 += (vs.z * scv[2] + shv[2]) * ws;
    a3 += (vs.w * scv[3] + shv[3]) * ws;
    ((float4*)outp)[node * TPN + q] = make_float4(a0, a1, a2, a3);
}

// ---------------- dense linear + bias + GELU (no stats) ----------------
template<int CIN, int COUT>
__global__ __launch_bounds__(256) void k_lin(const float* __restrict__ xin, const float* __restrict__ W,
                                             const float* __restrict__ bias, float* __restrict__ outp, int n){
    int i = blockIdx.x * 256 + threadIdx.x;
    int node = i / COUT, c = i % COUT;
    if (node >= n) return;
    float acc = bias[c];
#pragma unroll
    for (int k = 0; k < CIN; k++) acc += xin[node * CIN + k] * W[k * COUT + c];
    outp[i] = gelu_f(acc);
}

// ---------------- BN stats: 128-block grid-stride streaming reduction ----------------
template<int C>
__global__ __launch_bounds__(256) void k_stats(const float* __restrict__ h, float* __restrict__ stat, int n){
    constexpr int REP = 256 / C;            // rows processed per block-step
    int t = threadIdx.x;
    int rep = t / C;                         // replica index (row within step)
    int c = t % C;
    float s = 0.f, q = 0.f;
    for (int row = blockIdx.x * REP + rep; row < n; row += gridDim.x * REP){
        float v = h[(long long)row * C + c];
        s += v; q += v * v;
    }
    __shared__ float ss[256], sq[256];
    ss[t] = s; sq[t] = q;
    __syncthreads();
    for (int off = 128; off >= C; off >>= 1){
        if (t < off){ ss[t] += ss[t + off]; sq[t] += sq[t + off]; }
        __syncthreads();
    }
    if (t < C){
        atomicAdd(&stat[t], ss[t]);
        atomicAdd(&stat[128 + t], sq[t]);
    }
}

// ---------------- layer-4 linear + GELU + mean-pool, 8-node runs (sorted batch) ----------------
__global__ __launch_bounds__(256) void k_l4pool(const float* __restrict__ xin, const float* __restrict__ W,
                                                const float* __restrict__ bias, const int* __restrict__ batch,
                                                float* __restrict__ pool, float* __restrict__ cnt, int n){
    const int CIN = 64, COUT = 128, NT = 8;
    long long i = (long long)blockIdx.x * 256 + threadIdx.x;
    int tile = (int)(i / COUT), c = (int)(i % COUT);
    int n0 = tile * NT;
    if (n0 >= n) return;
    int nend = n0 + NT; if (nend > n) nend = n;
    float b = bias[c];
    float accp = 0.f, cloc = 0.f;
    int cur = batch[n0];
    for (int node = n0; node < nend; node++){
        int gr = batch[node];
        if (gr != cur){
            atomicAdd(&pool[cur * COUT + c], accp);
            if (c == 0) atomicAdd(&cnt[cur], cloc);
            accp = 0.f; cloc = 0.f; cur = gr;
        }
        float acc = b;
        const float4* xr = (const float4*)(xin + (long long)node * CIN);
#pragma unroll
        for (int k4 = 0; k4 < CIN / 4; k4++){
            float4 v = xr[k4];
            acc += v.x * W[(k4 * 4 + 0) * COUT + c];
            acc += v.y * W[(k4 * 4 + 1) * COUT + c];
            acc += v.z * W[(k4 * 4 + 2) * COUT + c];
            acc += v.w * W[(k4 * 4 + 3) * COUT + c];
        }
        accp += gelu_f(acc);
        cloc += 1.f;
    }
    atomicAdd(&pool[cur * COUT + c], accp);
    if (c == 0) atomicAdd(&cnt[cur], cloc);
}

// ---------------- MLP head: 256 graphs, one block each ----------------
__global__ __launch_bounds__(128) void k_mlp(const float* __restrict__ pool, const float* __restrict__ cnt,
                                             const float* __restrict__ yex,
                                             const float* __restrict__ lw1, const float* __restrict__ lb1,
                                             const float* __restrict__ lw2, const float* __restrict__ lb2,
                                             const float* __restrict__ lw3, const float* __restrict__ lb3,
                                             const float* __restrict__ lw4, const float* __restrict__ lb4,
                                             float* __restrict__ outp){
    int g = blockIdx.x;
    int t = threadIdx.x;
    __shared__ float z[136];
    __shared__ float z2[128];
    __shared__ float z3[64];
    __shared__ float z4[32];
    float cdiv = fmaxf(cnt[g], 1.0f);
    z[t] = pool[g * 128 + t] / cdiv;
    if (t < 7) z[128 + t] = yex[g * 7 + t];
    __syncthreads();
    {   // 135 -> 128
        float acc = lb1[t];
        for (int k = 0; k < 135; k++) acc += z[k] * lw1[k * 128 + t];
        z2[t] = gelu_f(acc);
    }
    __syncthreads();
    if (t < 64){   // 128 -> 64
        float acc = lb2[t];
        for (int k = 0; k < 128; k++) acc += z2[k] * lw2[k * 64 + t];
        z3[t] = gelu_f(acc);
    }
    __syncthreads();
    if (t < 32){   // 64 -> 32
        float acc = lb3[t];
        for (int k = 0; k < 64; k++) acc += z3[k] * lw3[k * 32 + t];
        z4[t] = gelu_f(acc);
    }
    __syncthreads();
    if (t < 2){    // 32 -> 2, sigmoid
        float acc = lb4[t];
        for (int k = 0; k < 32; k++) acc += z4[k] * lw4[k * 2 + t];
        outp[g * 2 + t] = 1.0f / (1.0f + expf(-acc));
    }
}

extern "C" void kernel_launch(void* const* d_in, const int* in_sizes, int n_in,
                              void* d_out, int out_size, void* d_ws, size_t ws_size,
                              hipStream_t stream) {
    const float* x     = (const float*)d_in[0];
    const int*   ei    = (const int*)  d_in[1];   // [2, E]: src = ei, dst = ei+E
    const int*   batch = (const int*)  d_in[2];
    const float* yex   = (const float*)d_in[3];
    const float* W1 = (const float*)d_in[4];  const float* b1 = (const float*)d_in[5];
    const float* W2 = (const float*)d_in[6];  const float* b2 = (const float*)d_in[7];
    const float* W3 = (const float*)d_in[8];  const float* b3 = (const float*)d_in[9];
    const float* W4 = (const float*)d_in[10]; const float* b4 = (const float*)d_in[11];
    const float* g1 = (const float*)d_in[12]; const float* be1 = (const float*)d_in[13];
    const float* g2 = (const float*)d_in[14]; const float* be2 = (const float*)d_in[15];
    const float* g3 = (const float*)d_in[16]; const float* be3 = (const float*)d_in[17];
    const float* lw1 = (const float*)d_in[18]; const float* lb1 = (const float*)d_in[19];
    const float* lw2 = (const float*)d_in[20]; const float* lb2 = (const float*)d_in[21];
    const float* lw3 = (const float*)d_in[22]; const float* lb3 = (const float*)d_in[23];
    const float* lw4 = (const float*)d_in[24]; const float* lb4 = (const float*)d_in[25];
    float* out = (float*)d_out;

    // ---- workspace carve (256B-aligned); zero-region first ----
    char* wsb = (char*)d_ws;
    size_t off = 0;
    auto alloc = [&](size_t elems) -> void* {
        void* p = wsb + off;
        off += ((elems * 4 + 255) / 256) * 256;
        return p;
    };
    int*   deg    = (int*)  alloc(NN);
    float* stats  = (float*)alloc(3 * 256);      // layer l: [l*256+c]=sum, [l*256+128+c]=sumsq
    float* pool   = (float*)alloc(GG * 128);
    float* cntv   = (float*)alloc(GG);
    float* agg1   = (float*)alloc(NN);
    size_t zero_bytes = off;
    int*   rp     = (int*)  alloc(NN + 1);
    int*   cursor = (int*)  alloc(NN);
    float* dis    = (float*)alloc(NN);
    int*   col    = (int*)  alloc(EE);
    float* wn     = (float*)alloc(EE);
    float* hbuf   = (float*)alloc((size_t)NN * 64);   // raw gelu outputs (<=64 ch)
    float* abuf   = (float*)alloc((size_t)NN * 64);   // aggregated inputs (<=64 ch)

    hipMemsetAsync(d_ws, 0, zero_bytes, stream);

    auto nb = [](long long total){ return (int)((total + 255) / 256); };

    // ---- graph norm precompute ----
    k_deg <<<nb(EE), 256, 0, stream>>>(ei + EE, deg, EE);
    k_scan<<<1, 1024, 0, stream>>>(deg, rp, cursor, dis, NN);
    k_fill<<<nb(EE), 256, 0, stream>>>(ei, ei + EE, dis, cursor, col, wn, EE);

    // ---- layer 1: aggregate x (C=1), 1->16 linear+gelu, stats ----
    k_agg1<<<nb(EE + NN), 256, 0, stream>>>(x, ei, ei + EE, dis, agg1, EE, NN);
    k_lin<1, 16><<<nb((long long)NN * 16), 256, 0, stream>>>(agg1, W1, b1, hbuf, NN);
    k_stats<16><<<128, 256, 0, stream>>>(hbuf, stats + 0, NN);

    // ---- layer 2: gather h1 (BN1 inline), 16->32 linear+gelu, stats ----
    k_gather<16><<<nb((long long)NN * 4), 256, 0, stream>>>(hbuf, rp, col, wn, dis, stats + 0, g1, be1, abuf, NN);
    k_lin<16, 32><<<nb((long long)NN * 32), 256, 0, stream>>>(abuf, W2, b2, hbuf, NN);
    k_stats<32><<<128, 256, 0, stream>>>(hbuf, stats + 256, NN);

    // ---- layer 3: gather h2 (BN2 inline), 32->64 linear+gelu, stats ----
    k_gather<32><<<nb((long long)NN * 8), 256, 0, stream>>>(hbuf, rp, col, wn, dis, stats + 256, g2, be2, abuf, NN);
    k_lin<32, 64><<<nb((long long)NN * 64), 256, 0, stream>>>(abuf, W3, b3, hbuf, NN);
    k_stats<64><<<128, 256, 0, stream>>>(hbuf, stats + 512, NN);

    // ---- layer 4: gather h3 (BN3 inline), fused 64->128 linear+gelu+pool ----
    k_gather<64><<<nb((long long)NN * 16), 256, 0, stream>>>(hbuf, rp, col, wn, dis, stats + 512, g3, be3, abuf, NN);
    k_l4pool<<<nb(((long long)NN + 7) / 8 * 128), 256, 0, stream>>>(abuf, W4, b4, batch, pool, cntv, NN);

    // ---- MLP head ----
    k_mlp<<<GG, 128, 0, stream>>>(pool, cntv, yex,
                                  lw1, lb1, lw2, lb2, lw3, lb3, lw4, lb4, out);
}

// Round 4
// 483.649 us; speedup vs baseline: 2.5543x; 1.3253x over previous
//
#include <hip/hip_runtime.h>
#include <math.h>

#define NN 50000
#define EE 800000
#define GG 256
#define NB_SCAN 196   // ceil(50000/256)

__device__ __forceinline__ float gelu_f(float v){
    return 0.5f * v * (1.0f + erff(v * 0.70710678118654752f));
}

// ---------------- degree count over dst ----------------
__global__ __launch_bounds__(256) void k_deg(const int* __restrict__ dst, int* __restrict__ deg, int e){
    int i = blockIdx.x * blockDim.x + threadIdx.x;
    if (i < e) atomicAdd(&deg[dst[i]], 1);
}

// ---------------- scan phase 1: per-block sums ----------------
__global__ __launch_bounds__(256) void k_bsum(const int* __restrict__ deg, int* __restrict__ bsum, int n){
    __shared__ int s[256];
    int t = threadIdx.x;
    int i = blockIdx.x * 256 + t;
    s[t] = (i < n) ? deg[i] : 0;
    __syncthreads();
    for (int off = 128; off > 0; off >>= 1){
        if (t < off) s[t] += s[t + off];
        __syncthreads();
    }
    if (t == 0) bsum[blockIdx.x] = s[0];
}

// ---------------- scan phase 2: single-block scan of partials (tiny) ----------------
__global__ __launch_bounds__(256) void k_pscan(const int* __restrict__ bsum, int* __restrict__ boff,
                                               int* __restrict__ rp, int nb, int n){
    __shared__ int s[256];
    int t = threadIdx.x;
    int v = (t < nb) ? bsum[t] : 0;
    s[t] = v;
    __syncthreads();
    for (int off = 1; off < 256; off <<= 1){
        int u = (t >= off) ? s[t - off] : 0;
        __syncthreads();
        s[t] += u;
        __syncthreads();
    }
    if (t < nb) boff[t] = s[t] - v;          // exclusive block offset
    if (t == nb - 1) rp[n] = s[t];           // total (= E)
}

// ---------------- scan phase 3: apply (in-block scan + block offset) ----------------
__global__ __launch_bounds__(256) void k_apply(const int* __restrict__ deg, const int* __restrict__ boff,
                                               int* __restrict__ rp, int* __restrict__ cursor,
                                               float* __restrict__ dis, int n){
    __shared__ int s[256];
    int t = threadIdx.x;
    int i = blockIdx.x * 256 + t;
    int d = (i < n) ? deg[i] : 0;
    s[t] = d;
    __syncthreads();
    for (int off = 1; off < 256; off <<= 1){
        int u = (t >= off) ? s[t - off] : 0;
        __syncthreads();
        s[t] += u;
        __syncthreads();
    }
    if (i < n){
        int excl = s[t] - d + boff[blockIdx.x];
        rp[i] = excl;
        cursor[i] = excl;
        dis[i] = rsqrtf((float)(d + 1));     // +1 self loop
    }
}

// ---------------- CSR fill ----------------
__global__ __launch_bounds__(256) void k_fill(const int* __restrict__ src, const int* __restrict__ dst,
                                              const float* __restrict__ dis, int* __restrict__ cursor,
                                              int* __restrict__ col, float* __restrict__ wn, int e){
    int i = blockIdx.x * blockDim.x + threadIdx.x;
    if (i < e){
        int d = dst[i], s = src[i];
        int p = atomicAdd(&cursor[d], 1);
        col[p] = s;
        wn[p]  = dis[s] * dis[d];
    }
}

// ---------------- layer-1 aggregation of x (C=1): edge-parallel atomics + self loop ----------------
__global__ __launch_bounds__(256) void k_agg1(const float* __restrict__ x, const int* __restrict__ src,
                                              const int* __restrict__ dst, const float* __restrict__ dis,
                                              float* __restrict__ agg, int e, int n){
    int i = blockIdx.x * blockDim.x + threadIdx.x;
    if (i < e){
        int s = src[i], d = dst[i];
        atomicAdd(&agg[d], x[s] * dis[s] * dis[d]);
    } else if (i < e + n){
        int node = i - e;
        float dn = dis[node];
        atomicAdd(&agg[node], dn * dn * x[node]);
    }
}

// ---------------- gather with inline BN of previous layer (float4, 2-edge unroll) ----------------
template<int C>
__global__ __launch_bounds__(256) void k_gather(const float* __restrict__ h, const int* __restrict__ rp,
                                                const int* __restrict__ col, const float* __restrict__ wn,
                                                const float* __restrict__ dis, const float* __restrict__ stat,
                                                const float* __restrict__ gamma, const float* __restrict__ beta,
                                                float* __restrict__ outp, int n){
    constexpr int TPN = C / 4;
    int i = blockIdx.x * 256 + threadIdx.x;
    int node = i / TPN, q = i % TPN;
    if (node >= n) return;
    int c0 = q * 4;
    const float invn = 1.0f / (float)NN;
    float scv[4], shv[4];
#pragma unroll
    for (int u = 0; u < 4; u++){
        float mean = stat[c0 + u] * invn;
        float var  = stat[128 + c0 + u] * invn - mean * mean;
        float sc   = gamma[c0 + u] * rsqrtf(var + 1e-5f);
        scv[u] = sc;
        shv[u] = beta[c0 + u] - mean * sc;
    }
    const float4* h4 = (const float4*)h;
    int beg = rp[node], end = rp[node + 1];
    float a0 = 0.f, a1 = 0.f, a2 = 0.f, a3 = 0.f;   // accumulates BN(h)*w
    float b0 = 0.f, b1 = 0.f, b2 = 0.f, b3 = 0.f;
    float wsum_a = 0.f, wsum_b = 0.f;               // accumulate w for the shift term
    int j = beg;
    for (; j + 1 < end; j += 2){
        int   c1i = col[j],     c2i = col[j + 1];
        float w1  = wn[j],      w2  = wn[j + 1];
        float4 v1 = h4[c1i * TPN + q];
        float4 v2 = h4[c2i * TPN + q];
        a0 += v1.x * w1; a1 += v1.y * w1; a2 += v1.z * w1; a3 += v1.w * w1; wsum_a += w1;
        b0 += v2.x * w2; b1 += v2.y * w2; b2 += v2.z * w2; b3 += v2.w * w2; wsum_b += w2;
    }
    if (j < end){
        float w1 = wn[j];
        float4 v1 = h4[col[j] * TPN + q];
        a0 += v1.x * w1; a1 += v1.y * w1; a2 += v1.z * w1; a3 += v1.w * w1; wsum_a += w1;
    }
    float dn = dis[node];
    float ws = dn * dn;
    float4 vs = h4[node * TPN + q];
    a0 += vs.x * ws; a1 += vs.y * ws; a2 += vs.z * ws; a3 += vs.w * ws; wsum_a += ws;
    a0 += b0; a1 += b1; a2 += b2; a3 += b3;
    float wsum = wsum_a + wsum_b;
    // BN is affine: sum_j w_j*(sc*v+sh) = sc*sum(w v) + sh*sum(w)
    float4 r = make_float4(a0 * scv[0] + shv[0] * wsum,
                           a1 * scv[1] + shv[1] * wsum,
                           a2 * scv[2] + shv[2] * wsum,
                           a3 * scv[3] + shv[3] * wsum);
    ((float4*)outp)[node * TPN + q] = r;
}

// ---------------- dense linear + bias + GELU ----------------
template<int CIN, int COUT>
__global__ __launch_bounds__(256) void k_lin(const float* __restrict__ xin, const float* __restrict__ W,
                                             const float* __restrict__ bias, float* __restrict__ outp, int n){
    int i = blockIdx.x * 256 + threadIdx.x;
    int node = i / COUT, c = i % COUT;
    if (node >= n) return;
    float acc = bias[c];
#pragma unroll
    for (int k = 0; k < CIN; k++) acc += xin[node * CIN + k] * W[k * COUT + c];
    outp[i] = gelu_f(acc);
}

// ---------------- BN stats: 128-block grid-stride streaming reduction ----------------
template<int C>
__global__ __launch_bounds__(256) void k_stats(const float* __restrict__ h, float* __restrict__ stat, int n){
    constexpr int REP = 256 / C;
    int t = threadIdx.x;
    int rep = t / C;
    int c = t % C;
    float s = 0.f, q = 0.f;
    for (int row = blockIdx.x * REP + rep; row < n; row += gridDim.x * REP){
        float v = h[(long long)row * C + c];
        s += v; q += v * v;
    }
    __shared__ float ss[256], sq[256];
    ss[t] = s; sq[t] = q;
    __syncthreads();
    for (int off = 128; off >= C; off >>= 1){
        if (t < off){ ss[t] += ss[t + off]; sq[t] += sq[t + off]; }
        __syncthreads();
    }
    if (t < C){
        atomicAdd(&stat[t], ss[t]);
        atomicAdd(&stat[128 + t], sq[t]);
    }
}

// ---------------- layer-4 linear + GELU + mean-pool, 8-node runs (sorted batch) ----------------
__global__ __launch_bounds__(256) void k_l4pool(const float* __restrict__ xin, const float* __restrict__ W,
                                                const float* __restrict__ bias, const int* __restrict__ batch,
                                                float* __restrict__ pool, float* __restrict__ cnt, int n){
    const int CIN = 64, COUT = 128, NT = 8;
    long long i = (long long)blockIdx.x * 256 + threadIdx.x;
    int tile = (int)(i / COUT), c = (int)(i % COUT);
    int n0 = tile * NT;
    if (n0 >= n) return;
    int nend = n0 + NT; if (nend > n) nend = n;
    float b = bias[c];
    float accp = 0.f, cloc = 0.f;
    int cur = batch[n0];
    for (int node = n0; node < nend; node++){
        int gr = batch[node];
        if (gr != cur){
            atomicAdd(&pool[cur * COUT + c], accp);
            if (c == 0) atomicAdd(&cnt[cur], cloc);
            accp = 0.f; cloc = 0.f; cur = gr;
        }
        float acc = b;
        const float4* xr = (const float4*)(xin + (long long)node * CIN);
#pragma unroll
        for (int k4 = 0; k4 < CIN / 4; k4++){
            float4 v = xr[k4];
            acc += v.x * W[(k4 * 4 + 0) * COUT + c];
            acc += v.y * W[(k4 * 4 + 1) * COUT + c];
            acc += v.z * W[(k4 * 4 + 2) * COUT + c];
            acc += v.w * W[(k4 * 4 + 3) * COUT + c];
        }
        accp += gelu_f(acc);
        cloc += 1.f;
    }
    atomicAdd(&pool[cur * COUT + c], accp);
    if (c == 0) atomicAdd(&cnt[cur], cloc);
}

// ---------------- MLP head: 256 graphs, one block each ----------------
__global__ __launch_bounds__(128) void k_mlp(const float* __restrict__ pool, const float* __restrict__ cnt,
                                             const float* __restrict__ yex,
                                             const float* __restrict__ lw1, const float* __restrict__ lb1,
                                             const float* __restrict__ lw2, const float* __restrict__ lb2,
                                             const float* __restrict__ lw3, const float* __restrict__ lb3,
                                             const float* __restrict__ lw4, const float* __restrict__ lb4,
                                             float* __restrict__ outp){
    int g = blockIdx.x;
    int t = threadIdx.x;
    __shared__ float z[136];
    __shared__ float z2[128];
    __shared__ float z3[64];
    __shared__ float z4[32];
    float cdiv = fmaxf(cnt[g], 1.0f);
    z[t] = pool[g * 128 + t] / cdiv;
    if (t < 7) z[128 + t] = yex[g * 7 + t];
    __syncthreads();
    {   // 135 -> 128
        float acc = lb1[t];
        for (int k = 0; k < 135; k++) acc += z[k] * lw1[k * 128 + t];
        z2[t] = gelu_f(acc);
    }
    __syncthreads();
    if (t < 64){   // 128 -> 64
        float acc = lb2[t];
        for (int k = 0; k < 128; k++) acc += z2[k] * lw2[k * 64 + t];
        z3[t] = gelu_f(acc);
    }
    __syncthreads();
    if (t < 32){   // 64 -> 32
        float acc = lb3[t];
        for (int k = 0; k < 64; k++) acc += z3[k] * lw3[k * 32 + t];
        z4[t] = gelu_f(acc);
    }
    __syncthreads();
    if (t < 2){    // 32 -> 2, sigmoid
        float acc = lb4[t];
        for (int k = 0; k < 32; k++) acc += z4[k] * lw4[k * 2 + t];
        outp[g * 2 + t] = 1.0f / (1.0f + expf(-acc));
    }
}

extern "C" void kernel_launch(void* const* d_in, const int* in_sizes, int n_in,
                              void* d_out, int out_size, void* d_ws, size_t ws_size,
                              hipStream_t stream) {
    const float* x     = (const float*)d_in[0];
    const int*   ei    = (const int*)  d_in[1];   // [2, E]: src = ei, dst = ei+E
    const int*   batch = (const int*)  d_in[2];
    const float* yex   = (const float*)d_in[3];
    const float* W1 = (const float*)d_in[4];  const float* b1 = (const float*)d_in[5];
    const float* W2 = (const float*)d_in[6];  const float* b2 = (const float*)d_in[7];
    const float* W3 = (const float*)d_in[8];  const float* b3 = (const float*)d_in[9];
    const float* W4 = (const float*)d_in[10]; const float* b4 = (const float*)d_in[11];
    const float* g1 = (const float*)d_in[12]; const float* be1 = (const float*)d_in[13];
    const float* g2 = (const float*)d_in[14]; const float* be2 = (const float*)d_in[15];
    const float* g3 = (const float*)d_in[16]; const float* be3 = (const float*)d_in[17];
    const float* lw1 = (const float*)d_in[18]; const float* lb1 = (const float*)d_in[19];
    const float* lw2 = (const float*)d_in[20]; const float* lb2 = (const float*)d_in[21];
    const float* lw3 = (const float*)d_in[22]; const float* lb3 = (const float*)d_in[23];
    const float* lw4 = (const float*)d_in[24]; const float* lb4 = (const float*)d_in[25];
    float* out = (float*)d_out;

    // ---- workspace carve (256B-aligned); zero-region first ----
    char* wsb = (char*)d_ws;
    size_t off = 0;
    auto alloc = [&](size_t elems) -> void* {
        void* p = wsb + off;
        off += ((elems * 4 + 255) / 256) * 256;
        return p;
    };
    int*   deg    = (int*)  alloc(NN);
    float* stats  = (float*)alloc(3 * 256);      // layer l: [l*256+c]=sum, [l*256+128+c]=sumsq
    float* pool   = (float*)alloc(GG * 128);
    float* cntv   = (float*)alloc(GG);
    float* agg1   = (float*)alloc(NN);
    size_t zero_bytes = off;
    int*   rp     = (int*)  alloc(NN + 1);
    int*   cursor = (int*)  alloc(NN);
    float* dis    = (float*)alloc(NN);
    int*   bsum   = (int*)  alloc(NB_SCAN);
    int*   boff   = (int*)  alloc(NB_SCAN);
    int*   col    = (int*)  alloc(EE);
    float* wn     = (float*)alloc(EE);
    float* hbuf   = (float*)alloc((size_t)NN * 64);   // raw gelu outputs (<=64 ch)
    float* abuf   = (float*)alloc((size_t)NN * 64);   // aggregated inputs (<=64 ch)

    hipMemsetAsync(d_ws, 0, zero_bytes, stream);

    auto nb = [](long long total){ return (int)((total + 255) / 256); };

    // ---- graph norm precompute (parallel scan) ----
    k_deg  <<<nb(EE), 256, 0, stream>>>(ei + EE, deg, EE);
    k_bsum <<<NB_SCAN, 256, 0, stream>>>(deg, bsum, NN);
    k_pscan<<<1, 256, 0, stream>>>(bsum, boff, rp, NB_SCAN, NN);
    k_apply<<<NB_SCAN, 256, 0, stream>>>(deg, boff, rp, cursor, dis, NN);
    k_fill <<<nb(EE), 256, 0, stream>>>(ei, ei + EE, dis, cursor, col, wn, EE);

    // ---- layer 1: aggregate x (C=1), 1->16 linear+gelu, stats ----
    k_agg1<<<nb(EE + NN), 256, 0, stream>>>(x, ei, ei + EE, dis, agg1, EE, NN);
    k_lin<1, 16><<<nb((long long)NN * 16), 256, 0, stream>>>(agg1, W1, b1, hbuf, NN);
    k_stats<16><<<128, 256, 0, stream>>>(hbuf, stats + 0, NN);

    // ---- layer 2: gather h1 (BN1 inline), 16->32 linear+gelu, stats ----
    k_gather<16><<<nb((long long)NN * 4), 256, 0, stream>>>(hbuf, rp, col, wn, dis, stats + 0, g1, be1, abuf, NN);
    k_lin<16, 32><<<nb((long long)NN * 32), 256, 0, stream>>>(abuf, W2, b2, hbuf, NN);
    k_stats<32><<<128, 256, 0, stream>>>(hbuf, stats + 256, NN);

    // ---- layer 3: gather h2 (BN2 inline), 32->64 linear+gelu, stats ----
    k_gather<32><<<nb((long long)NN * 8), 256, 0, stream>>>(hbuf, rp, col, wn, dis, stats + 256, g2, be2, abuf, NN);
    k_lin<32, 64><<<nb((long long)NN * 64), 256, 0, stream>>>(abuf, W3, b3, hbuf, NN);
    k_stats<64><<<128, 256, 0, stream>>>(hbuf, stats + 512, NN);

    // ---- layer 4: gather h3 (BN3 inline), fused 64->128 linear+gelu+pool ----
    k_gather<64><<<nb((long long)NN * 16), 256, 0, stream>>>(hbuf, rp, col, wn, dis, stats + 512, g3, be3, abuf, NN);
    k_l4pool<<<nb(((long long)NN + 7) / 8 * 128), 256, 0, stream>>>(abuf, W4, b4, batch, pool, cntv, NN);

    // ---- MLP head ----
    k_mlp<<<GG, 128, 0, stream>>>(pool, cntv, yex,
                                  lw1, lb1, lw2, lb2, lw3, lb3, lw4, lb4, out);
}